// Round 3
// baseline (127.575 us; speedup 1.0000x reference)
//
#include <hip/hip_runtime.h>
#include <hip/hip_bf16.h>
#include <math.h>

// Problem: B_SZ=2, L=2048, D=1024, N=16.  M = B_SZ*L = 4096.
// y[m,d] = x[m,d] * softplus((x@W1^T)[m,d] + b1[d]) * s[m]
// s[m]   = sum_n (x_m . W2_n + b2_n) * (x_m . W3_n + b3_n)
// A is unused (multiplies a zero-initialized h in the reference).
// Round-13:
//  * prep2: reverted to round-0/1 (256 blocks x 16 rows) — round-2's
//    8-row split doubled W2/W3 fetch + duplicate MFMA work: regression.
//  * gemm_bf: m97-class blocking. Per-wave output 32x32 -> 64x64
//    (4x4 fragments): 8 ds_read_b128 feed 16 MFMA (2:1 vs old 1:1),
//    halving LDS bytes/FLOP — the inner loop was LDS-pipe-bound
//    (16 waves x 16 ds_read x 12cyc = 3072 cyc vs 1280 cyc MFMA).
//    BM=BN=128, BK=64, 256 thr/4 waves, dbuf LDS 64 KB, one barrier
//    per K-step, grid 8x32=256 (1 block/CU), XCD swizzle (cpx=32).
// NOTE (round-6): never runtime-index MFMA fragment arrays (scratch demotion).
// NOTE (round-10): single-wave blocks kill latency hiding.
// NOTE (round-11): tile geometry alone is perf-neutral; bytes/FLOP is the lever.
// NOTE (round-12): don't split prep2 into half-rows (duplicated MFMA work).

typedef __bf16 bf16x8 __attribute__((ext_vector_type(8)));
typedef __bf16 bf16x4 __attribute__((ext_vector_type(4)));
typedef float  f32x4  __attribute__((ext_vector_type(4)));

#define MDIM 4096
#define KDIM 1024
#define NDIM 1024

// async global->LDS, 16B per lane; LDS dest = wave-uniform base + lane*16.
__device__ __forceinline__ void async16(const void* g, void* l) {
    __builtin_amdgcn_global_load_lds(
        (const __attribute__((address_space(1))) void*)g,
        (__attribute__((address_space(3))) void*)l, 16, 0, 0);
}

__device__ __forceinline__ float softplus_f(float z) {
    return fmaxf(z, 0.f) + log1pf(__expf(-fabsf(z)));
}

__device__ __forceinline__ bf16x8 cvt8(float4 v0, float4 v1) {
    bf16x8 h = { (__bf16)v0.x, (__bf16)v0.y, (__bf16)v0.z, (__bf16)v0.w,
                 (__bf16)v1.x, (__bf16)v1.y, (__bf16)v1.z, (__bf16)v1.w };
    return h;
}

// ====== prep2: x -> bf16 (LDS + global), W1 slice -> bf16, s via MFMA ======
// 256 blocks x 256 thr; block b owns x rows 16b..16b+15. 4 waves K-split
// (256 k each); Wc=[W2;W3] fragments read fp32 from L2-hot global + inline cvt.
__global__ __launch_bounds__(256)
void prep2(const float* __restrict__ x, const float* __restrict__ W1,
           const float* __restrict__ W2, const float* __restrict__ b2,
           const float* __restrict__ W3, const float* __restrict__ b3,
           __bf16* __restrict__ xb, __bf16* __restrict__ w1b,
           float* __restrict__ s) {
    __shared__ __align__(16) __bf16 xs[16 * 1032];   // 33 KB (+8 pad)
    __shared__ float red[4][2][16][16];              // 8 KB
    const int t = threadIdx.x;
    const int wave = t >> 6, lane = t & 63;
    const int lrow = lane & 15, quad = lane >> 4;
    const size_t m0 = (size_t)blockIdx.x * 16;
    const int wk0 = wave * 256;

    // ---- W1 slice -> bf16 (1024 float4 per block) ----
    {
        const float4* src = reinterpret_cast<const float4*>(W1) + (size_t)blockIdx.x * 1024;
        bf16x4* dst = reinterpret_cast<bf16x4*>(w1b) + (size_t)blockIdx.x * 1024;
#pragma unroll
        for (int i = 0; i < 4; ++i) {
            float4 v = src[i * 256 + t];
            bf16x4 h = { (__bf16)v.x, (__bf16)v.y, (__bf16)v.z, (__bf16)v.w };
            dst[i * 256 + t] = h;
        }
    }

    // ---- x rows: fp32 -> bf16, to LDS and global xb (coalesced) ----
#pragma unroll
    for (int i = 0; i < 16; ++i) {
        float4 v = *reinterpret_cast<const float4*>(x + (m0 + i) * KDIM + t * 4);
        bf16x4 h = { (__bf16)v.x, (__bf16)v.y, (__bf16)v.z, (__bf16)v.w };
        *reinterpret_cast<bf16x4*>(&xs[i * 1032 + t * 4]) = h;
        *reinterpret_cast<bf16x4*>(xb + (m0 + i) * KDIM + t * 4) = h;
    }
    __syncthreads();

    // ---- per-wave K-split MFMA; W fragments from fp32 global + inline cvt ----
    f32x4 acc[2] = {};
#pragma unroll
    for (int ks = 0; ks < 256; ks += 32) {
        bf16x8 a = *reinterpret_cast<const bf16x8*>(
            &xs[lrow * 1032 + wk0 + ks + quad * 8]);
        {
            const float* p2 = W2 + (size_t)lrow * KDIM + wk0 + ks + quad * 8;
            float4 v0 = *reinterpret_cast<const float4*>(p2);
            float4 v1 = *reinterpret_cast<const float4*>(p2 + 4);
            acc[0] = __builtin_amdgcn_mfma_f32_16x16x32_bf16(a, cvt8(v0, v1), acc[0], 0, 0, 0);
        }
        {
            const float* p3 = W3 + (size_t)lrow * KDIM + wk0 + ks + quad * 8;
            float4 v0 = *reinterpret_cast<const float4*>(p3);
            float4 v1 = *reinterpret_cast<const float4*>(p3 + 4);
            acc[1] = __builtin_amdgcn_mfma_f32_16x16x32_bf16(a, cvt8(v0, v1), acc[1], 0, 0, 0);
        }
    }
    // D layout: row = quad*4 + r (x-row), col = lrow (n)
#pragma unroll
    for (int r = 0; r < 4; ++r) {
        red[wave][0][quad * 4 + r][lrow] = acc[0][r];
        red[wave][1][quad * 4 + r][lrow] = acc[1][r];
    }
    __syncthreads();

    {
        const int row = t >> 4, n = t & 15;
        float Bv = red[0][0][row][n] + red[1][0][row][n]
                 + red[2][0][row][n] + red[3][0][row][n] + b2[n];
        float Cv = red[0][1][row][n] + red[1][1][row][n]
                 + red[2][1][row][n] + red[3][1][row][n] + b3[n];
        float p = Bv * Cv;
        p += __shfl_xor(p, 1);
        p += __shfl_xor(p, 2);
        p += __shfl_xor(p, 4);
        p += __shfl_xor(p, 8);
        if (n == 0) s[m0 + row] = p;
    }
}

// ============ main GEMM: y = x * softplus(xb@w1b^T + b1) * s ============
// Round-13: 128x128x64 tiles, 4 waves (256 thr), each wave 64x64 out
// (4x4 fragments, 8 ds_read feed 16 MFMA), double-buffered LDS (64 KB),
// stage(next)-before-compute(cur), one barrier per K-step.
// Grid 8x32 = 256 blocks = 1/CU, XCD swizzle cpx=32.
#define GBM 128
#define GBN 128
#define GBK 64
#define A_ELEMS (GBM * GBK)   // 8192 bf16 = 16 KB
#define B_ELEMS (GBN * GBK)   // 8192 bf16 = 16 KB
__global__ __launch_bounds__(256)
void gemm_bf(const __bf16* __restrict__ xb, const __bf16* __restrict__ w1b,
             const float* __restrict__ x, const float* __restrict__ b1,
             const float* __restrict__ s, float* __restrict__ y) {
    __shared__ __align__(16) __bf16 As[2 * A_ELEMS];  // 32 KB
    __shared__ __align__(16) __bf16 Bs[2 * B_ELEMS];  // 32 KB
    // bijective XCD swizzle: grid = 8 x 32 = 256 blocks, 256 % 8 == 0.
    const int cpx = 32;                            // 256 / 8
    const int bid0 = blockIdx.y * gridDim.x + blockIdx.x;
    const int bid = (bid0 & 7) * cpx + (bid0 >> 3);
    const int bm = bid >> 3, bn = bid & 7;         // gridDim.x == 8
    const int t = threadIdx.x;
    const int wave = t >> 6, lane = t & 63;
    const int wm = (wave >> 1) * 64, wn = (wave & 1) * 64;
    const int lrow = lane & 15, quad = lane >> 4;
    const int shi = lane >> 3;      // row within 8-row staging chunk
    const int spc = lane & 7;       // physical col group (16 B each)
    const size_t m0 = (size_t)bm * GBM, n0 = (size_t)bn * GBN;

    f32x4 acc[4][4] = {};

    // stage one K-tile into buffer `buf`: A = 16 chunks of 8 rows, B = 16.
    auto stage = [&](int buf, int k0) {
        __bf16* Ad = As + buf * A_ELEMS;
        __bf16* Bd = Bs + buf * B_ELEMS;
#pragma unroll
        for (int i = 0; i < 4; ++i) {
            int j = wave * 4 + i;             // 0..15
            int row = j * 8 + shi;            // 0..127
            int lcg = spc ^ (row & 7);        // logical col group to fetch
            async16(xb + (m0 + row) * KDIM + k0 + lcg * 8, Ad + j * 512);
        }
#pragma unroll
        for (int i = 0; i < 4; ++i) {
            int j = wave * 4 + i;             // 0..15
            int row = j * 8 + shi;            // 0..127
            int lcg = spc ^ (row & 7);
            async16(w1b + (n0 + row) * KDIM + k0 + lcg * 8, Bd + j * 512);
        }
    };

    auto compute = [&](int buf) {
        const __bf16* Ac = As + buf * A_ELEMS;
        const __bf16* Bc = Bs + buf * B_ELEMS;
#pragma unroll
        for (int kk = 0; kk < GBK; kk += 32) {
            const int cg = (kk >> 3) + quad;  // logical col group 0..7
            bf16x8 af[4], bfr[4];
#pragma unroll
            for (int mi = 0; mi < 4; ++mi) {
                int row = wm + mi * 16 + lrow;
                af[mi] = *reinterpret_cast<const bf16x8*>(
                    &Ac[row * GBK + ((cg ^ (row & 7)) << 3)]);
            }
#pragma unroll
            for (int ni = 0; ni < 4; ++ni) {
                int row = wn + ni * 16 + lrow;
                bfr[ni] = *reinterpret_cast<const bf16x8*>(
                    &Bc[row * GBK + ((cg ^ (row & 7)) << 3)]);
            }
#pragma unroll
            for (int mi = 0; mi < 4; ++mi)
#pragma unroll
                for (int ni = 0; ni < 4; ++ni)
                    acc[mi][ni] = __builtin_amdgcn_mfma_f32_16x16x32_bf16(
                        af[mi], bfr[ni], acc[mi][ni], 0, 0, 0);
        }
    };

    // 2-phase pipeline, 2 K-steps per iteration (static buffer indices).
    stage(0, 0);
    __syncthreads();
#pragma unroll 1
    for (int k0 = 0; k0 < KDIM; k0 += 2 * GBK) {
        if (k0 + GBK < KDIM) stage(1, k0 + GBK);
        compute(0);
        __syncthreads();                 // drains vmcnt (buf1 landed) + barrier
        if (k0 + 2 * GBK < KDIM) stage(0, k0 + 2 * GBK);
        compute(1);
        __syncthreads();
    }

    // ---- epilogue: y = x * softplus(acc + b1) * s ----
#pragma unroll
    for (int ni = 0; ni < 4; ++ni) {
        const size_t gn = n0 + wn + ni * 16 + lrow;
        const float bias = b1[gn];
#pragma unroll
        for (int mi = 0; mi < 4; ++mi) {
#pragma unroll
            for (int r = 0; r < 4; ++r) {
                const size_t gm = m0 + wm + mi * 16 + quad * 4 + r;
                float z = acc[mi][ni][r] + bias;
                y[gm * NDIM + gn] = x[gm * NDIM + gn] * softplus_f(z) * s[gm];
            }
        }
    }
}

// ================= fallback path (ws too small): round-0 kernels =============
__global__ __launch_bounds__(256)
void s_kernel_fb(const float* __restrict__ x,
                 const float* __restrict__ W2, const float* __restrict__ b2,
                 const float* __restrict__ W3, const float* __restrict__ b3,
                 float* __restrict__ s) {
    __shared__ float xs[1024];
    __shared__ float ps[8][32];
    __shared__ float bc[32];
    const int m = blockIdx.x;
    const int t = threadIdx.x;
    reinterpret_cast<float4*>(xs)[t] =
        reinterpret_cast<const float4*>(x + (size_t)m * 1024)[t];
    __syncthreads();
    const int n = t & 15;
    const int mat = (t >> 4) & 1;
    const int seg = t >> 5;
    const float* __restrict__ W = mat ? W3 : W2;
    const float* __restrict__ wr = W + (size_t)n * 1024 + seg * 128;
    const float* __restrict__ xr = xs + seg * 128;
    float p = 0.f;
#pragma unroll
    for (int i = 0; i < 128; i += 4) {
        float4 w4 = *reinterpret_cast<const float4*>(wr + i);
        float4 x4 = *reinterpret_cast<const float4*>(xr + i);
        p += w4.x * x4.x + w4.y * x4.y + w4.z * x4.z + w4.w * x4.w;
    }
    ps[seg][t & 31] = p;
    __syncthreads();
    if (t < 32) {
        float tot = 0.f;
#pragma unroll
        for (int g = 0; g < 8; ++g) tot += ps[g][t];
        tot += (t < 16) ? b2[t] : b3[t - 16];
        bc[t] = tot;
    }
    __syncthreads();
    if (t == 0) {
        float ss = 0.f;
#pragma unroll
        for (int nn = 0; nn < 16; ++nn) ss += bc[nn] * bc[16 + nn];
        s[m] = ss;
    }
}

#define BM 128
#define BN 64
#define BK 64
#define LDK 72
__global__ __launch_bounds__(256)
void gemm_fused_fb(const float* __restrict__ x, const float* __restrict__ W1,
                   const float* __restrict__ b1, const float* __restrict__ s,
                   float* __restrict__ y) {
    __shared__ __align__(16) __bf16 As[BM * LDK];
    __shared__ __align__(16) __bf16 Bs[BN * LDK];
    const int bm = blockIdx.y;
    const int bn = blockIdx.x;
    const int t = threadIdx.x;
    const int wave = t >> 6;
    const int lane = t & 63;
    const int wm = (wave >> 1) * 64;
    const int wn = (wave & 1) * 32;
    const int lrow = lane & 15;
    const int quad = lane >> 4;
    f32x4 acc[4][2] = {};
    const int rbase = t >> 4;
    const int scol = (t & 15) * 4;
    const float* __restrict__ xg = x + (size_t)(bm * BM) * KDIM + scol;
    const float* __restrict__ wg = W1 + (size_t)(bn * BN) * KDIM + scol;
    for (int k0 = 0; k0 < KDIM; k0 += BK) {
#pragma unroll
        for (int rr = 0; rr < 8; ++rr) {
            int row = rr * 16 + rbase;
            float4 v = *reinterpret_cast<const float4*>(xg + (size_t)row * KDIM + k0);
            bf16x4 h = { (__bf16)v.x, (__bf16)v.y, (__bf16)v.z, (__bf16)v.w };
            *reinterpret_cast<bf16x4*>(&As[row * LDK + scol]) = h;
        }
#pragma unroll
        for (int rr = 0; rr < 4; ++rr) {
            int row = rr * 16 + rbase;
            float4 v = *reinterpret_cast<const float4*>(wg + (size_t)row * KDIM + k0);
            bf16x4 h = { (__bf16)v.x, (__bf16)v.y, (__bf16)v.z, (__bf16)v.w };
            *reinterpret_cast<bf16x4*>(&Bs[row * LDK + scol]) = h;
        }
        __syncthreads();
#pragma unroll
        for (int kk = 0; kk < BK; kk += 32) {
            bf16x8 af[4];
            bf16x8 bfr[2];
#pragma unroll
            for (int mi = 0; mi < 4; ++mi)
                af[mi] = *reinterpret_cast<const bf16x8*>(
                    &As[(wm + mi * 16 + lrow) * LDK + kk + quad * 8]);
#pragma unroll
            for (int ni = 0; ni < 2; ++ni)
                bfr[ni] = *reinterpret_cast<const bf16x8*>(
                    &Bs[(wn + ni * 16 + lrow) * LDK + kk + quad * 8]);
#pragma unroll
            for (int mi = 0; mi < 4; ++mi)
#pragma unroll
                for (int ni = 0; ni < 2; ++ni)
                    acc[mi][ni] = __builtin_amdgcn_mfma_f32_16x16x32_bf16(
                        af[mi], bfr[ni], acc[mi][ni], 0, 0, 0);
        }
        __syncthreads();
    }
    const int gmb = bm * BM + wm;
    const int gnb = bn * BN + wn;
#pragma unroll
    for (int ni = 0; ni < 2; ++ni) {
        const int gn = gnb + ni * 16 + lrow;
        const float bias = b1[gn];
#pragma unroll
        for (int mi = 0; mi < 4; ++mi) {
            const int gm0 = gmb + mi * 16 + quad * 4;
#pragma unroll
            for (int r = 0; r < 4; ++r) {
                const int gm = gm0 + r;
                float z = acc[mi][ni][r] + bias;
                y[(size_t)gm * NDIM + gn] =
                    x[(size_t)gm * NDIM + gn] * softplus_f(z) * s[gm];
            }
        }
    }
}

extern "C" void kernel_launch(void* const* d_in, const int* in_sizes, int n_in,
                              void* d_out, int out_size, void* d_ws, size_t ws_size,
                              hipStream_t stream) {
    const float* x  = (const float*)d_in[0];
    const float* W1 = (const float*)d_in[1];
    const float* b1 = (const float*)d_in[2];
    const float* W2 = (const float*)d_in[3];
    const float* b2 = (const float*)d_in[4];
    const float* W3 = (const float*)d_in[5];
    const float* b3 = (const float*)d_in[6];
    // d_in[7] = A : unused

    float* y = (float*)d_out;

    const size_t XB_BYTES = (size_t)MDIM * KDIM * 2;   // 8 MB
    const size_t WB_BYTES = (size_t)NDIM * KDIM * 2;   // 2 MB
    const size_t S_BYTES  = (size_t)MDIM * 4;          // 16 KB

    if (ws_size >= XB_BYTES + WB_BYTES + S_BYTES) {
        __bf16* xb  = (__bf16*)d_ws;
        __bf16* w1b = (__bf16*)((char*)d_ws + XB_BYTES);
        float*  s   = (float*)((char*)d_ws + XB_BYTES + WB_BYTES);
        prep2<<<dim3(MDIM / 16), dim3(256), 0, stream>>>(
            x, W1, W2, b2, W3, b3, xb, w1b, s);
        gemm_bf<<<dim3(NDIM / GBN, MDIM / GBM), dim3(256), 0, stream>>>(
            xb, w1b, x, b1, s, y);
    } else {
        float* s = (float*)d_ws;
        s_kernel_fb<<<dim3(MDIM), dim3(256), 0, stream>>>(x, W2, b2, W3, b3, s);
        gemm_fused_fb<<<dim3(NDIM / BN, MDIM / BM), dim3(256), 0, stream>>>(x, W1, b1, s, y);
    }
}

// Round 4
// 116.221 us; speedup vs baseline: 1.0977x; 1.0977x over previous
//
#include <hip/hip_runtime.h>
#include <hip/hip_bf16.h>
#include <math.h>

// Problem: B_SZ=2, L=2048, D=1024, N=16.  M = B_SZ*L = 4096.
// y[m,d] = x[m,d] * softplus((x@W1^T)[m,d] + b1[d]) * s[m]
// s[m]   = sum_n (x_m . W2_n + b2_n) * (x_m . W3_n + b3_n)
// A is unused (multiplies a zero-initialized h in the reference).
// Round-14:
//  * gemm_bf: 64x64x128 tile, TWO waves/block (128 thr), each wave owns a
//    32x64 output strip (acc 2x4): 6 ds_read_b128 feed 8 MFMA per kk
//    (ds:MFMA 0.75 vs baseline 1.0), 32 MFMA/wave/K-step (2x baseline) —
//    m92->m93 ladder step executed WITHIN our grid constraint.
//    Single-buffered 32 KB LDS, m97-style 2-barrier loop, grid (16,64)=1024
//    = 4 blocks/CU resident (LDS cap 5), 8 waves/CU, 4 barrier domains.
//  * prep2: round-0 known-good version, untouched.
// Measured ladder for THIS shape: {64², 4w, 4/CU, 1:1}=330 TF;
// {128x64, 16w/CU, 1:1}=330; {128², 1/CU, 2:1, dbuf}=200 TF (MfmaUtil 6.8%,
// latency-serialized — grid-starved).  Blocks/CU and MFMA-per-drain are the
// levers; staging bytes are L2/L3-absorbed (FETCH 20.8 MB).
// NOTE (round-6): never runtime-index MFMA fragment arrays (scratch demotion).
// NOTE (round-10/13): <2 blocks/CU (or 1-wave blocks) kill latency hiding.
// NOTE (round-12): don't split prep2 into half-rows (duplicated MFMA work).

typedef __bf16 bf16x8 __attribute__((ext_vector_type(8)));
typedef __bf16 bf16x4 __attribute__((ext_vector_type(4)));
typedef float  f32x4  __attribute__((ext_vector_type(4)));

#define MDIM 4096
#define KDIM 1024
#define NDIM 1024

// async global->LDS, 16B per lane; LDS dest = wave-uniform base + lane*16.
__device__ __forceinline__ void async16(const void* g, void* l) {
    __builtin_amdgcn_global_load_lds(
        (const __attribute__((address_space(1))) void*)g,
        (__attribute__((address_space(3))) void*)l, 16, 0, 0);
}

__device__ __forceinline__ float softplus_f(float z) {
    return fmaxf(z, 0.f) + log1pf(__expf(-fabsf(z)));
}

__device__ __forceinline__ bf16x8 cvt8(float4 v0, float4 v1) {
    bf16x8 h = { (__bf16)v0.x, (__bf16)v0.y, (__bf16)v0.z, (__bf16)v0.w,
                 (__bf16)v1.x, (__bf16)v1.y, (__bf16)v1.z, (__bf16)v1.w };
    return h;
}

// ====== prep2: x -> bf16 (LDS + global), W1 slice -> bf16, s via MFMA ======
// 256 blocks x 256 thr; block b owns x rows 16b..16b+15. 4 waves K-split
// (256 k each); Wc=[W2;W3] fragments read fp32 from L2-hot global + inline cvt.
__global__ __launch_bounds__(256)
void prep2(const float* __restrict__ x, const float* __restrict__ W1,
           const float* __restrict__ W2, const float* __restrict__ b2,
           const float* __restrict__ W3, const float* __restrict__ b3,
           __bf16* __restrict__ xb, __bf16* __restrict__ w1b,
           float* __restrict__ s) {
    __shared__ __align__(16) __bf16 xs[16 * 1032];   // 33 KB (+8 pad)
    __shared__ float red[4][2][16][16];              // 8 KB
    const int t = threadIdx.x;
    const int wave = t >> 6, lane = t & 63;
    const int lrow = lane & 15, quad = lane >> 4;
    const size_t m0 = (size_t)blockIdx.x * 16;
    const int wk0 = wave * 256;

    // ---- W1 slice -> bf16 (1024 float4 per block) ----
    {
        const float4* src = reinterpret_cast<const float4*>(W1) + (size_t)blockIdx.x * 1024;
        bf16x4* dst = reinterpret_cast<bf16x4*>(w1b) + (size_t)blockIdx.x * 1024;
#pragma unroll
        for (int i = 0; i < 4; ++i) {
            float4 v = src[i * 256 + t];
            bf16x4 h = { (__bf16)v.x, (__bf16)v.y, (__bf16)v.z, (__bf16)v.w };
            dst[i * 256 + t] = h;
        }
    }

    // ---- x rows: fp32 -> bf16, to LDS and global xb (coalesced) ----
#pragma unroll
    for (int i = 0; i < 16; ++i) {
        float4 v = *reinterpret_cast<const float4*>(x + (m0 + i) * KDIM + t * 4);
        bf16x4 h = { (__bf16)v.x, (__bf16)v.y, (__bf16)v.z, (__bf16)v.w };
        *reinterpret_cast<bf16x4*>(&xs[i * 1032 + t * 4]) = h;
        *reinterpret_cast<bf16x4*>(xb + (m0 + i) * KDIM + t * 4) = h;
    }
    __syncthreads();

    // ---- per-wave K-split MFMA; W fragments from fp32 global + inline cvt ----
    f32x4 acc[2] = {};
#pragma unroll
    for (int ks = 0; ks < 256; ks += 32) {
        bf16x8 a = *reinterpret_cast<const bf16x8*>(
            &xs[lrow * 1032 + wk0 + ks + quad * 8]);
        {
            const float* p2 = W2 + (size_t)lrow * KDIM + wk0 + ks + quad * 8;
            float4 v0 = *reinterpret_cast<const float4*>(p2);
            float4 v1 = *reinterpret_cast<const float4*>(p2 + 4);
            acc[0] = __builtin_amdgcn_mfma_f32_16x16x32_bf16(a, cvt8(v0, v1), acc[0], 0, 0, 0);
        }
        {
            const float* p3 = W3 + (size_t)lrow * KDIM + wk0 + ks + quad * 8;
            float4 v0 = *reinterpret_cast<const float4*>(p3);
            float4 v1 = *reinterpret_cast<const float4*>(p3 + 4);
            acc[1] = __builtin_amdgcn_mfma_f32_16x16x32_bf16(a, cvt8(v0, v1), acc[1], 0, 0, 0);
        }
    }
    // D layout: row = quad*4 + r (x-row), col = lrow (n)
#pragma unroll
    for (int r = 0; r < 4; ++r) {
        red[wave][0][quad * 4 + r][lrow] = acc[0][r];
        red[wave][1][quad * 4 + r][lrow] = acc[1][r];
    }
    __syncthreads();

    {
        const int row = t >> 4, n = t & 15;
        float Bv = red[0][0][row][n] + red[1][0][row][n]
                 + red[2][0][row][n] + red[3][0][row][n] + b2[n];
        float Cv = red[0][1][row][n] + red[1][1][row][n]
                 + red[2][1][row][n] + red[3][1][row][n] + b3[n];
        float p = Bv * Cv;
        p += __shfl_xor(p, 1);
        p += __shfl_xor(p, 2);
        p += __shfl_xor(p, 4);
        p += __shfl_xor(p, 8);
        if (n == 0) s[m0 + row] = p;
    }
}

// ============ main GEMM: y = x * softplus(xb@w1b^T + b1) * s ============
// Round-14: 64x64x128 tile, 2 waves (128 thr), wave = 32x64 out (acc 2x4,
// 6 ds_read -> 8 MFMA per kk), single-buffered 32 KB LDS, 2-barrier loop,
// grid (16,64) = 1024 blocks = 4/CU resident, XCD swizzle (cpx=128).
#define GBM 64
#define GBN 64
#define GBK 128
__global__ __launch_bounds__(128)
void gemm_bf(const __bf16* __restrict__ xb, const __bf16* __restrict__ w1b,
             const float* __restrict__ x, const float* __restrict__ b1,
             const float* __restrict__ s, float* __restrict__ y) {
    __shared__ __align__(16) __bf16 As[GBM * GBK];  // 16 KB
    __shared__ __align__(16) __bf16 Bs[GBN * GBK];  // 16 KB
    // bijective XCD swizzle: grid = 16 x 64 = 1024 blocks, 1024 % 8 == 0.
    const int cpx = 128;                           // 1024 / 8
    const int bid0 = blockIdx.y * gridDim.x + blockIdx.x;
    const int bid = (bid0 & 7) * cpx + (bid0 >> 3);
    const int bm = bid >> 4, bn = bid & 15;        // gridDim.x == 16
    const int t = threadIdx.x;                     // 0..127
    const int wave = t >> 6, lane = t & 63;
    const int wm = wave * 32;                      // wave's 32-row M strip
    const int lrow = lane & 15, quad = lane >> 4;
    const int sr  = lane >> 4;      // row within 4-row staging chunk
    const int pcg = lane & 15;      // physical col group (8 bf16 each)
    const size_t m0 = (size_t)bm * GBM, n0 = (size_t)bn * GBN;

    f32x4 acc[2][4] = {};

    for (int k0 = 0; k0 < KDIM; k0 += GBK) {
        // stage: A = 16 chunks of 1 KB (4 rows each), B = 16; 8+8 per wave.
#pragma unroll
        for (int i = 0; i < 8; ++i) {
            int q = wave * 8 + i;             // 0..15
            int row = q * 4 + sr;             // 0..63
            int lcg = pcg ^ (row & 15);       // logical col group to fetch
            async16(xb + (m0 + row) * KDIM + k0 + lcg * 8, &As[q * 512]);
        }
#pragma unroll
        for (int i = 0; i < 8; ++i) {
            int q = wave * 8 + i;             // 0..15
            int row = q * 4 + sr;             // 0..63
            int lcg = pcg ^ (row & 15);
            async16(w1b + (n0 + row) * KDIM + k0 + lcg * 8, &Bs[q * 512]);
        }
        __syncthreads();

#pragma unroll
        for (int kk = 0; kk < GBK; kk += 32) {
            const int cg = (kk >> 3) + quad;  // logical col group 0..15
            bf16x8 af[2], bfr[4];
#pragma unroll
            for (int mi = 0; mi < 2; ++mi) {
                int row = wm + mi * 16 + lrow;
                af[mi] = *reinterpret_cast<const bf16x8*>(
                    &As[row * GBK + ((cg ^ (row & 15)) << 3)]);
            }
#pragma unroll
            for (int ni = 0; ni < 4; ++ni) {
                int row = ni * 16 + lrow;
                bfr[ni] = *reinterpret_cast<const bf16x8*>(
                    &Bs[row * GBK + ((cg ^ (row & 15)) << 3)]);
            }
#pragma unroll
            for (int mi = 0; mi < 2; ++mi)
#pragma unroll
                for (int ni = 0; ni < 4; ++ni)
                    acc[mi][ni] = __builtin_amdgcn_mfma_f32_16x16x32_bf16(
                        af[mi], bfr[ni], acc[mi][ni], 0, 0, 0);
        }
        __syncthreads();
    }

    // ---- epilogue: y = x * softplus(acc + b1) * s ----
#pragma unroll
    for (int ni = 0; ni < 4; ++ni) {
        const size_t gn = n0 + ni * 16 + lrow;
        const float bias = b1[gn];
#pragma unroll
        for (int mi = 0; mi < 2; ++mi) {
#pragma unroll
            for (int r = 0; r < 4; ++r) {
                const size_t gm = m0 + wm + mi * 16 + quad * 4 + r;
                float z = acc[mi][ni][r] + bias;
                y[gm * NDIM + gn] = x[gm * NDIM + gn] * softplus_f(z) * s[gm];
            }
        }
    }
}

// ================= fallback path (ws too small): round-0 kernels =============
__global__ __launch_bounds__(256)
void s_kernel_fb(const float* __restrict__ x,
                 const float* __restrict__ W2, const float* __restrict__ b2,
                 const float* __restrict__ W3, const float* __restrict__ b3,
                 float* __restrict__ s) {
    __shared__ float xs[1024];
    __shared__ float ps[8][32];
    __shared__ float bc[32];
    const int m = blockIdx.x;
    const int t = threadIdx.x;
    reinterpret_cast<float4*>(xs)[t] =
        reinterpret_cast<const float4*>(x + (size_t)m * 1024)[t];
    __syncthreads();
    const int n = t & 15;
    const int mat = (t >> 4) & 1;
    const int seg = t >> 5;
    const float* __restrict__ W = mat ? W3 : W2;
    const float* __restrict__ wr = W + (size_t)n * 1024 + seg * 128;
    const float* __restrict__ xr = xs + seg * 128;
    float p = 0.f;
#pragma unroll
    for (int i = 0; i < 128; i += 4) {
        float4 w4 = *reinterpret_cast<const float4*>(wr + i);
        float4 x4 = *reinterpret_cast<const float4*>(xr + i);
        p += w4.x * x4.x + w4.y * x4.y + w4.z * x4.z + w4.w * x4.w;
    }
    ps[seg][t & 31] = p;
    __syncthreads();
    if (t < 32) {
        float tot = 0.f;
#pragma unroll
        for (int g = 0; g < 8; ++g) tot += ps[g][t];
        tot += (t < 16) ? b2[t] : b3[t - 16];
        bc[t] = tot;
    }
    __syncthreads();
    if (t == 0) {
        float ss = 0.f;
#pragma unroll
        for (int nn = 0; nn < 16; ++nn) ss += bc[nn] * bc[16 + nn];
        s[m] = ss;
    }
}

#define BM 128
#define BN 64
#define BK 64
#define LDK 72
__global__ __launch_bounds__(256)
void gemm_fused_fb(const float* __restrict__ x, const float* __restrict__ W1,
                   const float* __restrict__ b1, const float* __restrict__ s,
                   float* __restrict__ y) {
    __shared__ __align__(16) __bf16 As[BM * LDK];
    __shared__ __align__(16) __bf16 Bs[BN * LDK];
    const int bm = blockIdx.y;
    const int bn = blockIdx.x;
    const int t = threadIdx.x;
    const int wave = t >> 6;
    const int lane = t & 63;
    const int wm = (wave >> 1) * 64;
    const int wn = (wave & 1) * 32;
    const int lrow = lane & 15;
    const int quad = lane >> 4;
    f32x4 acc[4][2] = {};
    const int rbase = t >> 4;
    const int scol = (t & 15) * 4;
    const float* __restrict__ xg = x + (size_t)(bm * BM) * KDIM + scol;
    const float* __restrict__ wg = W1 + (size_t)(bn * BN) * KDIM + scol;
    for (int k0 = 0; k0 < KDIM; k0 += BK) {
#pragma unroll
        for (int rr = 0; rr < 8; ++rr) {
            int row = rr * 16 + rbase;
            float4 v = *reinterpret_cast<const float4*>(xg + (size_t)row * KDIM + k0);
            bf16x4 h = { (__bf16)v.x, (__bf16)v.y, (__bf16)v.z, (__bf16)v.w };
            *reinterpret_cast<bf16x4*>(&As[row * LDK + scol]) = h;
        }
#pragma unroll
        for (int rr = 0; rr < 4; ++rr) {
            int row = rr * 16 + rbase;
            float4 v = *reinterpret_cast<const float4*>(wg + (size_t)row * KDIM + k0);
            bf16x4 h = { (__bf16)v.x, (__bf16)v.y, (__bf16)v.z, (__bf16)v.w };
            *reinterpret_cast<bf16x4*>(&Bs[row * LDK + scol]) = h;
        }
        __syncthreads();
#pragma unroll
        for (int kk = 0; kk < BK; kk += 32) {
            bf16x8 af[4];
            bf16x8 bfr[2];
#pragma unroll
            for (int mi = 0; mi < 4; ++mi)
                af[mi] = *reinterpret_cast<const bf16x8*>(
                    &As[(wm + mi * 16 + lrow) * LDK + kk + quad * 8]);
#pragma unroll
            for (int ni = 0; ni < 2; ++ni)
                bfr[ni] = *reinterpret_cast<const bf16x8*>(
                    &Bs[(wn + ni * 16 + lrow) * LDK + kk + quad * 8]);
#pragma unroll
            for (int mi = 0; mi < 4; ++mi)
#pragma unroll
                for (int ni = 0; ni < 2; ++ni)
                    acc[mi][ni] = __builtin_amdgcn_mfma_f32_16x16x32_bf16(
                        af[mi], bfr[ni], acc[mi][ni], 0, 0, 0);
        }
        __syncthreads();
    }
    const int gmb = bm * BM + wm;
    const int gnb = bn * BN + wn;
#pragma unroll
    for (int ni = 0; ni < 2; ++ni) {
        const int gn = gnb + ni * 16 + lrow;
        const float bias = b1[gn];
#pragma unroll
        for (int mi = 0; mi < 4; ++mi) {
            const int gm0 = gmb + mi * 16 + quad * 4;
#pragma unroll
            for (int r = 0; r < 4; ++r) {
                const int gm = gm0 + r;
                float z = acc[mi][ni][r] + bias;
                y[(size_t)gm * NDIM + gn] =
                    x[(size_t)gm * NDIM + gn] * softplus_f(z) * s[gm];
            }
        }
    }
}

extern "C" void kernel_launch(void* const* d_in, const int* in_sizes, int n_in,
                              void* d_out, int out_size, void* d_ws, size_t ws_size,
                              hipStream_t stream) {
    const float* x  = (const float*)d_in[0];
    const float* W1 = (const float*)d_in[1];
    const float* b1 = (const float*)d_in[2];
    const float* W2 = (const float*)d_in[3];
    const float* b2 = (const float*)d_in[4];
    const float* W3 = (const float*)d_in[5];
    const float* b3 = (const float*)d_in[6];
    // d_in[7] = A : unused

    float* y = (float*)d_out;

    const size_t XB_BYTES = (size_t)MDIM * KDIM * 2;   // 8 MB
    const size_t WB_BYTES = (size_t)NDIM * KDIM * 2;   // 2 MB
    const size_t S_BYTES  = (size_t)MDIM * 4;          // 16 KB

    if (ws_size >= XB_BYTES + WB_BYTES + S_BYTES) {
        __bf16* xb  = (__bf16*)d_ws;
        __bf16* w1b = (__bf16*)((char*)d_ws + XB_BYTES);
        float*  s   = (float*)((char*)d_ws + XB_BYTES + WB_BYTES);
        prep2<<<dim3(MDIM / 16), dim3(256), 0, stream>>>(
            x, W1, W2, b2, W3, b3, xb, w1b, s);
        gemm_bf<<<dim3(NDIM / GBN, MDIM / GBM), dim3(128), 0, stream>>>(
            xb, w1b, x, b1, s, y);
    } else {
        float* s = (float*)d_ws;
        s_kernel_fb<<<dim3(MDIM), dim3(256), 0, stream>>>(x, W2, b2, W3, b3, s);
        gemm_fused_fb<<<dim3(NDIM / BN, MDIM / BM), dim3(256), 0, stream>>>(x, W1, b1, s, y);
    }
}

// Round 5
// 112.079 us; speedup vs baseline: 1.1383x; 1.0370x over previous
//
#include <hip/hip_runtime.h>
#include <hip/hip_bf16.h>
#include <math.h>

// Problem: B_SZ=2, L=2048, D=1024, N=16.  M = B_SZ*L = 4096.
// y[m,d] = x[m,d] * softplus((x@W1^T)[m,d] + b1[d]) * s[m]
// s[m]   = sum_n (x_m . W2_n + b2_n) * (x_m . W3_n + b3_n)
// A is unused (multiplies a zero-initialized h in the reference).
// Round-15: restore the 111-µs round-9 structure EXACTLY (64x64x128 tile,
// 4 waves/256 thr, single-buf 32 KB LDS, 16-colgroup XOR swizzle, grid
// (16,64)=1024 blocks, 4-5 blocks/CU, 16 waves/CU) and make ONE change:
// MFMA shape 16x16x32 -> 32x32x16.  Same LDS bytes, same staging, same
// occupancy; per-MFMA FLOP/cyc +22% (m119: 2495 vs 2075 TF ceiling) and
// inner loop 32 -> 24 instructions per K-step (16 ds_read + 8 MFMA).
// C/D layout (m74/m101 verified): col=lane&31, row=(reg&3)+8*(reg>>2)+4*(lane>>5).
// A/B frag: row/col=lane&31, k=(lane>>5)*8+j  (one ds_read_b128 per operand/kk).
// Session ladder (this shape): waves/CU is the dominant variable —
//   16 w/CU + 1:1 ratio = 330 TF (R0/R1); 8 w/CU + 0.75 = ~280 (R4);
//   4 w/CU + 0.5 + dbuf = 200 (R3, MfmaUtil 6.8%).  Never trade occupancy.
// NOTE (round-6): never runtime-index MFMA fragment arrays (scratch demotion).
// NOTE (round-12): don't split prep2 into half-rows (duplicated MFMA work).
// NOTE: fill (44.6 µs) + harness memsets are a fixed ~66 µs of the total;
// kernel deltas map ~1:1 into dur_us (R3: gemm +16.5 -> total +16.5).

typedef __bf16 bf16x8 __attribute__((ext_vector_type(8)));
typedef __bf16 bf16x4 __attribute__((ext_vector_type(4)));
typedef float  f32x4  __attribute__((ext_vector_type(4)));
typedef float  f32x16 __attribute__((ext_vector_type(16)));

#define MDIM 4096
#define KDIM 1024
#define NDIM 1024

// async global->LDS, 16B per lane; LDS dest = wave-uniform base + lane*16.
__device__ __forceinline__ void async16(const void* g, void* l) {
    __builtin_amdgcn_global_load_lds(
        (const __attribute__((address_space(1))) void*)g,
        (__attribute__((address_space(3))) void*)l, 16, 0, 0);
}

__device__ __forceinline__ float softplus_f(float z) {
    return fmaxf(z, 0.f) + log1pf(__expf(-fabsf(z)));
}

__device__ __forceinline__ bf16x8 cvt8(float4 v0, float4 v1) {
    bf16x8 h = { (__bf16)v0.x, (__bf16)v0.y, (__bf16)v0.z, (__bf16)v0.w,
                 (__bf16)v1.x, (__bf16)v1.y, (__bf16)v1.z, (__bf16)v1.w };
    return h;
}

// ====== prep2: x -> bf16 (LDS + global), W1 slice -> bf16, s via MFMA ======
// 256 blocks x 256 thr; block b owns x rows 16b..16b+15. 4 waves K-split
// (256 k each); Wc=[W2;W3] fragments read fp32 from L2-hot global + inline cvt.
__global__ __launch_bounds__(256)
void prep2(const float* __restrict__ x, const float* __restrict__ W1,
           const float* __restrict__ W2, const float* __restrict__ b2,
           const float* __restrict__ W3, const float* __restrict__ b3,
           __bf16* __restrict__ xb, __bf16* __restrict__ w1b,
           float* __restrict__ s) {
    __shared__ __align__(16) __bf16 xs[16 * 1032];   // 33 KB (+8 pad)
    __shared__ float red[4][2][16][16];              // 8 KB
    const int t = threadIdx.x;
    const int wave = t >> 6, lane = t & 63;
    const int lrow = lane & 15, quad = lane >> 4;
    const size_t m0 = (size_t)blockIdx.x * 16;
    const int wk0 = wave * 256;

    // ---- W1 slice -> bf16 (1024 float4 per block) ----
    {
        const float4* src = reinterpret_cast<const float4*>(W1) + (size_t)blockIdx.x * 1024;
        bf16x4* dst = reinterpret_cast<bf16x4*>(w1b) + (size_t)blockIdx.x * 1024;
#pragma unroll
        for (int i = 0; i < 4; ++i) {
            float4 v = src[i * 256 + t];
            bf16x4 h = { (__bf16)v.x, (__bf16)v.y, (__bf16)v.z, (__bf16)v.w };
            dst[i * 256 + t] = h;
        }
    }

    // ---- x rows: fp32 -> bf16, to LDS and global xb (coalesced) ----
#pragma unroll
    for (int i = 0; i < 16; ++i) {
        float4 v = *reinterpret_cast<const float4*>(x + (m0 + i) * KDIM + t * 4);
        bf16x4 h = { (__bf16)v.x, (__bf16)v.y, (__bf16)v.z, (__bf16)v.w };
        *reinterpret_cast<bf16x4*>(&xs[i * 1032 + t * 4]) = h;
        *reinterpret_cast<bf16x4*>(xb + (m0 + i) * KDIM + t * 4) = h;
    }
    __syncthreads();

    // ---- per-wave K-split MFMA; W fragments from fp32 global + inline cvt ----
    f32x4 acc[2] = {};
#pragma unroll
    for (int ks = 0; ks < 256; ks += 32) {
        bf16x8 a = *reinterpret_cast<const bf16x8*>(
            &xs[lrow * 1032 + wk0 + ks + quad * 8]);
        {
            const float* p2 = W2 + (size_t)lrow * KDIM + wk0 + ks + quad * 8;
            float4 v0 = *reinterpret_cast<const float4*>(p2);
            float4 v1 = *reinterpret_cast<const float4*>(p2 + 4);
            acc[0] = __builtin_amdgcn_mfma_f32_16x16x32_bf16(a, cvt8(v0, v1), acc[0], 0, 0, 0);
        }
        {
            const float* p3 = W3 + (size_t)lrow * KDIM + wk0 + ks + quad * 8;
            float4 v0 = *reinterpret_cast<const float4*>(p3);
            float4 v1 = *reinterpret_cast<const float4*>(p3 + 4);
            acc[1] = __builtin_amdgcn_mfma_f32_16x16x32_bf16(a, cvt8(v0, v1), acc[1], 0, 0, 0);
        }
    }
    // D layout: row = quad*4 + r (x-row), col = lrow (n)
#pragma unroll
    for (int r = 0; r < 4; ++r) {
        red[wave][0][quad * 4 + r][lrow] = acc[0][r];
        red[wave][1][quad * 4 + r][lrow] = acc[1][r];
    }
    __syncthreads();

    {
        const int row = t >> 4, n = t & 15;
        float Bv = red[0][0][row][n] + red[1][0][row][n]
                 + red[2][0][row][n] + red[3][0][row][n] + b2[n];
        float Cv = red[0][1][row][n] + red[1][1][row][n]
                 + red[2][1][row][n] + red[3][1][row][n] + b3[n];
        float p = Bv * Cv;
        p += __shfl_xor(p, 1);
        p += __shfl_xor(p, 2);
        p += __shfl_xor(p, 4);
        p += __shfl_xor(p, 8);
        if (n == 0) s[m0 + row] = p;
    }
}

// ============ main GEMM: y = x * softplus(xb@w1b^T + b1) * s ============
// Round-15: round-9 structure (64x64x128, 4 waves, 1024 blocks, XOR-swizzled
// async16 staging, 2 barriers/K-step) with 32x32x16 MFMA: per kk=16 one
// ds_read_b128 per operand + one fat MFMA; 16 ds + 8 MFMA per K-step.
#define GBM 64
#define GBN 64
#define GBK 128
__global__ __launch_bounds__(256)
void gemm_bf(const __bf16* __restrict__ xb, const __bf16* __restrict__ w1b,
             const float* __restrict__ x, const float* __restrict__ b1,
             const float* __restrict__ s, float* __restrict__ y) {
    __shared__ __align__(16) __bf16 As[GBM * GBK];  // 16 KB
    __shared__ __align__(16) __bf16 Bs[GBN * GBK];  // 16 KB
    const int bm = blockIdx.y, bn = blockIdx.x;
    const int t = threadIdx.x;
    const int wave = t >> 6, lane = t & 63;
    const int wm = (wave >> 1) * 32, wn = (wave & 1) * 32;
    const int l31 = lane & 31;      // MFMA row/col within the 32-tile
    const int khalf = lane >> 5;    // k-half selector (0: k0..7, 1: k8..15)
    const int sr  = lane >> 4;      // row within 4-row staging chunk
    const int pcg = lane & 15;      // physical col group (8 bf16 each)
    const size_t m0 = (size_t)bm * GBM, n0 = (size_t)bn * GBN;

    f32x16 acc = {};

    for (int k0 = 0; k0 < KDIM; k0 += GBK) {
#pragma unroll
        for (int i = 0; i < 4; ++i) {
            int q = wave * 4 + i;             // 0..15
            int row = q * 4 + sr;             // 0..63
            int lcg = pcg ^ (row & 15);       // logical col group to fetch
            async16(xb + (m0 + row) * KDIM + k0 + lcg * 8, &As[q * 512]);
        }
#pragma unroll
        for (int i = 0; i < 4; ++i) {
            int q = wave * 4 + i;             // 0..15
            int row = q * 4 + sr;             // 0..63
            int lcg = pcg ^ (row & 15);
            async16(w1b + (n0 + row) * KDIM + k0 + lcg * 8, &Bs[q * 512]);
        }
        __syncthreads();

#pragma unroll
        for (int kk = 0; kk < GBK; kk += 16) {
            const int cg = (kk >> 3) + khalf;   // logical col group 0..15
            const int arow = wm + l31;          // arow&15 == lane&15
            const int brow = wn + l31;
            bf16x8 a = *reinterpret_cast<const bf16x8*>(
                &As[arow * GBK + ((cg ^ (arow & 15)) << 3)]);
            bf16x8 b = *reinterpret_cast<const bf16x8*>(
                &Bs[brow * GBK + ((cg ^ (brow & 15)) << 3)]);
            acc = __builtin_amdgcn_mfma_f32_32x32x16_bf16(a, b, acc, 0, 0, 0);
        }
        __syncthreads();
    }

    // ---- epilogue: y = x * softplus(acc + b1) * s ----
    // C/D: col = lane&31, row = (reg&3) + 8*(reg>>2) + 4*(lane>>5)
    {
        const size_t gn = n0 + wn + l31;
        const float bias = b1[gn];
        const int rbase = khalf * 4;
#pragma unroll
        for (int r = 0; r < 16; ++r) {
            const int row = (r & 3) + 8 * (r >> 2) + rbase;
            const size_t gm = m0 + wm + row;
            float z = acc[r] + bias;
            y[gm * NDIM + gn] = x[gm * NDIM + gn] * softplus_f(z) * s[gm];
        }
    }
}

// ================= fallback path (ws too small): round-0 kernels =============
__global__ __launch_bounds__(256)
void s_kernel_fb(const float* __restrict__ x,
                 const float* __restrict__ W2, const float* __restrict__ b2,
                 const float* __restrict__ W3, const float* __restrict__ b3,
                 float* __restrict__ s) {
    __shared__ float xs[1024];
    __shared__ float ps[8][32];
    __shared__ float bc[32];
    const int m = blockIdx.x;
    const int t = threadIdx.x;
    reinterpret_cast<float4*>(xs)[t] =
        reinterpret_cast<const float4*>(x + (size_t)m * 1024)[t];
    __syncthreads();
    const int n = t & 15;
    const int mat = (t >> 4) & 1;
    const int seg = t >> 5;
    const float* __restrict__ W = mat ? W3 : W2;
    const float* __restrict__ wr = W + (size_t)n * 1024 + seg * 128;
    const float* __restrict__ xr = xs + seg * 128;
    float p = 0.f;
#pragma unroll
    for (int i = 0; i < 128; i += 4) {
        float4 w4 = *reinterpret_cast<const float4*>(wr + i);
        float4 x4 = *reinterpret_cast<const float4*>(xr + i);
        p += w4.x * x4.x + w4.y * x4.y + w4.z * x4.z + w4.w * x4.w;
    }
    ps[seg][t & 31] = p;
    __syncthreads();
    if (t < 32) {
        float tot = 0.f;
#pragma unroll
        for (int g = 0; g < 8; ++g) tot += ps[g][t];
        tot += (t < 16) ? b2[t] : b3[t - 16];
        bc[t] = tot;
    }
    __syncthreads();
    if (t == 0) {
        float ss = 0.f;
#pragma unroll
        for (int nn = 0; nn < 16; ++nn) ss += bc[nn] * bc[16 + nn];
        s[m] = ss;
    }
}

#define BM 128
#define BN 64
#define BK 64
#define LDK 72
__global__ __launch_bounds__(256)
void gemm_fused_fb(const float* __restrict__ x, const float* __restrict__ W1,
                   const float* __restrict__ b1, const float* __restrict__ s,
                   float* __restrict__ y) {
    __shared__ __align__(16) __bf16 As[BM * LDK];
    __shared__ __align__(16) __bf16 Bs[BN * LDK];
    const int bm = blockIdx.y;
    const int bn = blockIdx.x;
    const int t = threadIdx.x;
    const int wave = t >> 6;
    const int lane = t & 63;
    const int wm = (wave >> 1) * 64;
    const int wn = (wave & 1) * 32;
    const int lrow = lane & 15;
    const int quad = lane >> 4;
    f32x4 acc[4][2] = {};
    const int rbase = t >> 4;
    const int scol = (t & 15) * 4;
    const float* __restrict__ xg = x + (size_t)(bm * BM) * KDIM + scol;
    const float* __restrict__ wg = W1 + (size_t)(bn * BN) * KDIM + scol;
    for (int k0 = 0; k0 < KDIM; k0 += BK) {
#pragma unroll
        for (int rr = 0; rr < 8; ++rr) {
            int row = rr * 16 + rbase;
            float4 v = *reinterpret_cast<const float4*>(xg + (size_t)row * KDIM + k0);
            bf16x4 h = { (__bf16)v.x, (__bf16)v.y, (__bf16)v.z, (__bf16)v.w };
            *reinterpret_cast<bf16x4*>(&As[row * LDK + scol]) = h;
        }
#pragma unroll
        for (int rr = 0; rr < 4; ++rr) {
            int row = rr * 16 + rbase;
            float4 v = *reinterpret_cast<const float4*>(wg + (size_t)row * KDIM + k0);
            bf16x4 h = { (__bf16)v.x, (__bf16)v.y, (__bf16)v.z, (__bf16)v.w };
            *reinterpret_cast<bf16x4*>(&Bs[row * LDK + scol]) = h;
        }
        __syncthreads();
#pragma unroll
        for (int kk = 0; kk < BK; kk += 32) {
            bf16x8 af[4];
            bf16x8 bfr[2];
#pragma unroll
            for (int mi = 0; mi < 4; ++mi)
                af[mi] = *reinterpret_cast<const bf16x8*>(
                    &As[(wm + mi * 16 + lrow) * LDK + kk + quad * 8]);
#pragma unroll
            for (int ni = 0; ni < 2; ++ni)
                bfr[ni] = *reinterpret_cast<const bf16x8*>(
                    &Bs[(wn + ni * 16 + lrow) * LDK + kk + quad * 8]);
#pragma unroll
            for (int mi = 0; mi < 4; ++mi)
#pragma unroll
                for (int ni = 0; ni < 2; ++ni)
                    acc[mi][ni] = __builtin_amdgcn_mfma_f32_16x16x32_bf16(
                        af[mi], bfr[ni], acc[mi][ni], 0, 0, 0);
        }
        __syncthreads();
    }
    const int gmb = bm * BM + wm;
    const int gnb = bn * BN + wn;
#pragma unroll
    for (int ni = 0; ni < 2; ++ni) {
        const int gn = gnb + ni * 16 + lrow;
        const float bias = b1[gn];
#pragma unroll
        for (int mi = 0; mi < 4; ++mi) {
            const int gm0 = gmb + mi * 16 + quad * 4;
#pragma unroll
            for (int r = 0; r < 4; ++r) {
                const int gm = gm0 + r;
                float z = acc[mi][ni][r] + bias;
                y[(size_t)gm * NDIM + gn] =
                    x[(size_t)gm * NDIM + gn] * softplus_f(z) * s[gm];
            }
        }
    }
}

extern "C" void kernel_launch(void* const* d_in, const int* in_sizes, int n_in,
                              void* d_out, int out_size, void* d_ws, size_t ws_size,
                              hipStream_t stream) {
    const float* x  = (const float*)d_in[0];
    const float* W1 = (const float*)d_in[1];
    const float* b1 = (const float*)d_in[2];
    const float* W2 = (const float*)d_in[3];
    const float* b2 = (const float*)d_in[4];
    const float* W3 = (const float*)d_in[5];
    const float* b3 = (const float*)d_in[6];
    // d_in[7] = A : unused

    float* y = (float*)d_out;

    const size_t XB_BYTES = (size_t)MDIM * KDIM * 2;   // 8 MB
    const size_t WB_BYTES = (size_t)NDIM * KDIM * 2;   // 2 MB
    const size_t S_BYTES  = (size_t)MDIM * 4;          // 16 KB

    if (ws_size >= XB_BYTES + WB_BYTES + S_BYTES) {
        __bf16* xb  = (__bf16*)d_ws;
        __bf16* w1b = (__bf16*)((char*)d_ws + XB_BYTES);
        float*  s   = (float*)((char*)d_ws + XB_BYTES + WB_BYTES);
        prep2<<<dim3(MDIM / 16), dim3(256), 0, stream>>>(
            x, W1, W2, b2, W3, b3, xb, w1b, s);
        gemm_bf<<<dim3(NDIM / GBN, MDIM / GBM), dim3(256), 0, stream>>>(
            xb, w1b, x, b1, s, y);
    } else {
        float* s = (float*)d_ws;
        s_kernel_fb<<<dim3(MDIM), dim3(256), 0, stream>>>(x, W2, b2, W3, b3, s);
        gemm_fused_fb<<<dim3(NDIM / BN, MDIM / BM), dim3(256), 0, stream>>>(x, W1, b1, s, y);
    }
}